// Round 14
// baseline (111.985 us; speedup 1.0000x reference)
//
#include <hip/hip_runtime.h>
#include <hip/hip_bf16.h>

#define NDIM  4096
#define MROWS 8192
#define PREAL 969
#define KP    1024   // 32 K-tiles of 32
#define NT32  32
#define NWFOLD 1024  // wfold blocks: 16 x 64

typedef unsigned short u16;
typedef __attribute__((ext_vector_type(8))) __bf16 bf16x8;
typedef __attribute__((ext_vector_type(8))) u16 u16x8;
typedef __attribute__((ext_vector_type(4))) float f32x4;

__device__ __forceinline__ u16 bf16rne(float f) {
  unsigned int u = __builtin_bit_cast(unsigned int, f);
  u += 0x7fffu + ((u >> 16) & 1u);
  return (u16)(u >> 16);
}

// -------- compile-time multiset table: TBL.v[p] = (i<<10)|(j<<5)|k, idx 16 = "1"; -1 = pad --------
struct Tbl { int v[KP]; };
constexpr Tbl make_table() {
  Tbl t{};
  for (int p = 0; p < KP; ++p) t.v[p] = -1;
  int p = 0;
  t.v[p++] = (16 << 10) | (16 << 5) | 16;
  for (int i = 0; i < 16; ++i) t.v[p++] = (i << 10) | (16 << 5) | 16;
  for (int i = 0; i < 16; ++i)
    for (int j = i; j < 16; ++j) t.v[p++] = (i << 10) | (j << 5) | 16;
  for (int i = 0; i < 16; ++i)
    for (int j = i; j < 16; ++j)
      for (int k = j; k < 16; ++k) t.v[p++] = (i << 10) | (j << 5) | k;
  return t;
}
__device__ constexpr Tbl TBL = make_table();

// -------- merged prep: blocks [0,NWFOLD) fold W; blocks [NWFOLD, NWFOLD+MROWS) build features --------
__global__ void prep_kernel(const float* __restrict__ z, const float* __restrict__ W,
                            const float* __restrict__ bias,
                            u16* __restrict__ xb, u16* __restrict__ wfbt) {
  __shared__ float tile[64][65];
  __shared__ float zs[17];
  const int bx = blockIdx.x;
  const int tid = threadIdx.x;

  if (bx < NWFOLD) {
    const int p0 = (bx & 15) * 64;
    const int d0 = (bx >> 4) * 64;
    const int d4 = (tid & 15) * 4;
    const int rb = tid >> 4;
    const int dd = d0 + d4;
#pragma unroll
    for (int pp = 0; pp < 4; ++pp) {
      const int r = pp * 16 + rb;
      const int p = p0 + r;
      const int enc = TBL.v[p];
      f32x4 v = {0.f, 0.f, 0.f, 0.f};
      if (enc >= 0) {
        const int i = enc >> 10, j = (enc >> 5) & 31, k = enc & 31;
        if (k == 16) {
          if (j == 16) {
            if (i == 16) {
              v = *reinterpret_cast<const f32x4*>(W + dd);
              f32x4 bb = *reinterpret_cast<const f32x4*>(bias + dd);
              v.x += bb.x; v.y += bb.y; v.z += bb.z; v.w += bb.w;
            } else {
              v = *reinterpret_cast<const f32x4*>(W + (size_t)(1 + i) * NDIM + dd);
            }
          } else {
            v = *reinterpret_cast<const f32x4*>(W + (size_t)(17 + i * 16 + j) * NDIM + dd);
            if (i != j) {
              f32x4 w2 = *reinterpret_cast<const f32x4*>(W + (size_t)(17 + j * 16 + i) * NDIM + dd);
              v.x += w2.x; v.y += w2.y; v.z += w2.z; v.w += w2.w;
            }
          }
        } else {
          int rows[6];
          int nr = 0;
          rows[nr++] = 273 + i * 256 + j * 16 + k;
          if (i == j && j == k) {
          } else if (i == j) {
            rows[nr++] = 273 + i * 256 + k * 16 + i;
            rows[nr++] = 273 + k * 256 + i * 16 + i;
          } else if (j == k) {
            rows[nr++] = 273 + j * 256 + i * 16 + j;
            rows[nr++] = 273 + j * 256 + j * 16 + i;
          } else {
            rows[nr++] = 273 + i * 256 + k * 16 + j;
            rows[nr++] = 273 + j * 256 + i * 16 + k;
            rows[nr++] = 273 + j * 256 + k * 16 + i;
            rows[nr++] = 273 + k * 256 + i * 16 + j;
            rows[nr++] = 273 + k * 256 + j * 16 + i;
          }
          v = *reinterpret_cast<const f32x4*>(W + (size_t)rows[0] * NDIM + dd);
          for (int s = 1; s < nr; ++s) {
            f32x4 w2 = *reinterpret_cast<const f32x4*>(W + (size_t)rows[s] * NDIM + dd);
            v.x += w2.x; v.y += w2.y; v.z += w2.z; v.w += w2.w;
          }
        }
      }
#pragma unroll
      for (int jj = 0; jj < 4; ++jj) tile[r][d4 + jj] = v[jj];
    }
    __syncthreads();
#pragma unroll
    for (int round = 0; round < 2; ++round) {
      const int v = round * 256 + tid;
      const int d = v >> 3;
      const int tg = v & 7;
      u16x8 pack;
#pragma unroll
      for (int e = 0; e < 8; ++e) pack[e] = bf16rne(tile[tg * 8 + e][d]);
      *reinterpret_cast<u16x8*>(wfbt + (size_t)(d0 + d) * KP + p0 + tg * 8) = pack;
    }
  } else {
    const int row = bx - NWFOLD;
    if (tid < 16) zs[tid] = z[row * 16 + tid];
    if (tid == 16) zs[16] = 1.0f;
    __syncthreads();
    u16* xrow = xb + (size_t)row * KP;
    for (int g = tid; g < KP / 8; g += 256) {
      u16x8 pack;
#pragma unroll
      for (int e = 0; e < 8; ++e) {
        const int enc = TBL.v[g * 8 + e];
        float v = 0.0f;
        if (enc >= 0) v = zs[enc >> 10] * (zs[(enc >> 5) & 31] * zs[enc & 31]);
        pack[e] = bf16rne(v);
      }
      *reinterpret_cast<u16x8*>(xrow + g * 8) = pack;
    }
  }
}

// ---- 128x128 GEMM, BK=32, triple-buffer (48 KiB) -> 3 blocks/CU, depth-2 prefetch ----
#define GLOAD(gp, lp)                                                                     \
  __builtin_amdgcn_global_load_lds((const __attribute__((address_space(1))) unsigned int*)(gp), \
                                   (__attribute__((address_space(3))) unsigned int*)(lp), 16, 0, 0)

__device__ __forceinline__ void bar() {
  asm volatile("" ::: "memory");
  __builtin_amdgcn_s_barrier();
  asm volatile("" ::: "memory");
}

__global__ __launch_bounds__(256, 3) void gemm_kernel(const u16* __restrict__ xb,
                                                      const u16* __restrict__ wbt,
                                                      float* __restrict__ out) {
  __shared__ u16 lds[3 * 8192];  // 48 KiB: 3 x (A[128][32] + B[128][32])

  // XCD swizzle (R13-validated): 2048 blocks; window 4Mx8N fits L2
  const int bid  = blockIdx.x;
  const int xcd  = bid & 7;
  const int idx  = bid >> 3;            // 0..255 within XCD
  const int win  = idx >> 5;            // 0..7
  const int w    = idx & 31;
  const int mtl  = (win >> 2) * 4 + (w >> 3);
  const int ntl  = (win & 3) * 8 + (w & 7);
  const int brow = (xcd * 8 + mtl) * 128;
  const int bcol = ntl * 128;

  const int tid  = threadIdx.x;
  const int lane = tid & 63;
  const int wid  = tid >> 6;   // 0..3
  const int wr   = wid >> 1;   // 0..1
  const int wc   = wid & 1;    // 0..1
  const int f    = lane & 15;
  const int q    = lane >> 4;
  const int fsw  = (f >> 1) & 3;   // read-side swizzle bits (row>>1)&3, row = 16m + f

  // staging: lane covers row (lane>>2) of its 16-row group, physical chunk lane&3;
  // global source pre-swizzled: chunk = (lane&3) ^ ((lane>>3)&3)  [= (row>>1)&3]
  const int srow = lane >> 2;
  const int sch  = ((lane & 3) ^ ((lane >> 3) & 3)) * 8;
  const u16* gA = xb  + (size_t)(brow + srow) * KP + sch;
  const u16* gB = wbt + (size_t)(bcol + srow) * KP + sch;
  const int r1 = wid * 16;        // wave's 16-row groups: r1 and r1+64
  const int r2 = 64 + wid * 16;

// stage full K-tile U (A+B, 4 gloads/wave) into buffer BUFI
#define STG_TILE(BUFI, U) do {                                                       \
    u16* _a = lds + (BUFI) * 8192;                                                   \
    u16* _b = _a + 4096;                                                             \
    GLOAD(gA + (size_t)r1 * KP + (U) * 32, _a + r1 * 32);                            \
    GLOAD(gA + (size_t)r2 * KP + (U) * 32, _a + r2 * 32);                            \
    GLOAD(gB + (size_t)r1 * KP + (U) * 32, _b + r1 * 32);                            \
    GLOAD(gB + (size_t)r2 * KP + (U) * 32, _b + r2 * 32);                            \
  } while (0)

// swizzled ds_read_b128: row stride 32 u16 (64 B); phys chunk = q ^ ((row>>1)&3)
#define RD_A(mi) (*reinterpret_cast<const bf16x8*>(bufA + (wr * 64 + (mi) * 16 + f) * 32 + (q ^ fsw) * 8))
#define RD_B(ni) (*reinterpret_cast<const bf16x8*>(bufB + (wc * 64 + (ni) * 16 + f) * 32 + (q ^ fsw) * 8))

// one K-tile: stage t+2, read 8 frags, 16 MFMA, fence confirms t+1, single barrier.
// STG into buf[(CUR+2)%3] = buffer tile t-1 read -> all its reads retired before the
// t-1 end-barrier (they fed MFMAs pre-barrier) -> race-free at tile start.
#define TILE_BODY(CUR, STGB, U) do {                                                 \
    const u16* bufA = lds + (CUR) * 8192;                                            \
    const u16* bufB = bufA + 4096;                                                   \
    STG_TILE(STGB, U);                                                               \
    _Pragma("unroll") for (int _i = 0; _i < 4; ++_i) a_[_i] = RD_A(_i);              \
    _Pragma("unroll") for (int _i = 0; _i < 4; ++_i) b_[_i] = RD_B(_i);              \
    __builtin_amdgcn_s_setprio(1);                                                   \
    _Pragma("unroll") for (int _m = 0; _m < 4; ++_m)                                 \
    _Pragma("unroll") for (int _n = 0; _n < 4; ++_n)                                 \
      acc[_m][_n] = __builtin_amdgcn_mfma_f32_16x16x32_bf16(a_[_m], b_[_n], acc[_m][_n], 0, 0, 0); \
    __builtin_amdgcn_s_setprio(0);                                                   \
    asm volatile("s_waitcnt vmcnt(4)" ::: "memory");                                 \
    bar();                                                                           \
  } while (0)

// final tiles (no staging)
#define TILE_NOSTG(CUR, FENCE) do {                                                  \
    const u16* bufA = lds + (CUR) * 8192;                                            \
    const u16* bufB = bufA + 4096;                                                   \
    _Pragma("unroll") for (int _i = 0; _i < 4; ++_i) a_[_i] = RD_A(_i);              \
    _Pragma("unroll") for (int _i = 0; _i < 4; ++_i) b_[_i] = RD_B(_i);              \
    __builtin_amdgcn_s_setprio(1);                                                   \
    _Pragma("unroll") for (int _m = 0; _m < 4; ++_m)                                 \
    _Pragma("unroll") for (int _n = 0; _n < 4; ++_n)                                 \
      acc[_m][_n] = __builtin_amdgcn_mfma_f32_16x16x32_bf16(a_[_m], b_[_n], acc[_m][_n], 0, 0, 0); \
    __builtin_amdgcn_s_setprio(0);                                                   \
    FENCE;                                                                           \
  } while (0)

  f32x4 acc[4][4] = {};
  bf16x8 a_[4], b_[4];

  // prologue: stage tiles 0,1; per-wave vmcnt(4) -> tile0 resident, tile1 in flight
  STG_TILE(0, 0);
  STG_TILE(1, 1);
  asm volatile("s_waitcnt vmcnt(4)" ::: "memory");
  bar();

  // tiles 0..29 (10 x 3-unrolled, static buffer indices), staging t+2 each
  for (int t3 = 0; t3 < 30; t3 += 3) {
    TILE_BODY(0, 2, t3 + 2);
    TILE_BODY(1, 0, t3 + 3);
    TILE_BODY(2, 1, t3 + 4);
  }
  // tile 30 (buf0): no stage; drain tile31's loads
  TILE_NOSTG(0, { asm volatile("s_waitcnt vmcnt(0)" ::: "memory"); bar(); });
  // tile 31 (buf1): fully resident
  TILE_NOSTG(1, {});

  // epilogue: C/D layout col = lane&15, row = (lane>>4)*4 + j
  const int r0 = brow + wr * 64 + q * 4;
  const int c0 = bcol + wc * 64 + f;
#pragma unroll
  for (int mi = 0; mi < 4; ++mi)
#pragma unroll
    for (int ni = 0; ni < 4; ++ni) {
#pragma unroll
      for (int j = 0; j < 4; ++j)
        out[(size_t)(r0 + mi * 16 + j) * NDIM + (c0 + ni * 16)] = acc[mi][ni][j];
    }
}

// ---------------- fallback (ws too small): correct fp32 path on raw features ----------------
__global__ void fallback_kernel(const float* __restrict__ z, const float* __restrict__ W,
                                const float* __restrict__ bias, float* __restrict__ out) {
  __shared__ float feat[4369];
  const int row = blockIdx.x;
  const int tid = threadIdx.x;
  for (int t = tid; t < 4369; t += 256) {
    float v;
    if (t == 0) v = 1.0f;
    else if (t < 17) v = z[row * 16 + t - 1];
    else if (t < 273) { int u = t - 17; v = z[row * 16 + (u >> 4)] * z[row * 16 + (u & 15)]; }
    else { int u = t - 273; v = z[row * 16 + ((u >> 8) & 15)] * (z[row * 16 + ((u >> 4) & 15)] * z[row * 16 + (u & 15)]); }
    feat[t] = v;
  }
  __syncthreads();
  float acc[16];
#pragma unroll
  for (int j = 0; j < 16; ++j) acc[j] = bias[tid + 256 * j];
  for (int t = 0; t < 4369; ++t) {
    const float fv = feat[t];
    const float* wrow = W + (size_t)t * NDIM;
#pragma unroll
    for (int j = 0; j < 16; ++j) acc[j] = fmaf(fv, wrow[tid + 256 * j], acc[j]);
  }
  float* orow = out + (size_t)row * NDIM;
#pragma unroll
  for (int j = 0; j < 16; ++j) orow[tid + 256 * j] = acc[j];
}

extern "C" void kernel_launch(void* const* d_in, const int* in_sizes, int n_in,
                              void* d_out, int out_size, void* d_ws, size_t ws_size,
                              hipStream_t stream) {
  const float* z = (const float*)d_in[0];
  const float* W = (const float*)d_in[1];
  const float* b = (const float*)d_in[2];
  float* out = (float*)d_out;

  const size_t xb_elems  = (size_t)MROWS * KP;
  const size_t wbt_elems = (size_t)NDIM * KP;
  const size_t need = (xb_elems + wbt_elems) * sizeof(u16);

  if (ws_size >= need) {
    u16* xb  = (u16*)d_ws;
    u16* wbt = xb + xb_elems;
    prep_kernel<<<NWFOLD + MROWS, 256, 0, stream>>>(z, W, b, xb, wbt);
    gemm_kernel<<<(MROWS / 128) * (NDIM / 128), 256, 0, stream>>>(xb, wbt, out);
  } else {
    fallback_kernel<<<MROWS, 256, 0, stream>>>(z, W, b, out);
  }
}